// Round 2
// baseline (452.736 us; speedup 1.0000x reference)
//
#include <hip/hip_runtime.h>
#include <math.h>

// Shapes fixed by setup_inputs(): B=8, N=8192, M=512 clusters, S=64 samples.
#define BB 8
#define NN 8192
#define MM 512
#define SS 64

// d_out layout (flat, return order): new_xyz f32[8*512*3] | idx (as f32!)[8*512*64] |
// attention f32[8*512] | orientation f32[8*512]
// NOTE: harness reads the WHOLE out buffer as float32 and compares the idx chunk
// numerically -> indices must be stored as float values, not int bit patterns.
#define OUT_IDX   (BB*MM*3)              // 12288
#define OUT_ATT   (OUT_IDX + BB*MM*SS)   // 274432
#define OUT_ORI   (OUT_ATT + BB*MM)      // 278528

__global__ __launch_bounds__(256, 3) void feat3d_cluster_kernel(
    const float* __restrict__ xyz,
    const float* __restrict__ W1, const float* __restrict__ b1,
    const float* __restrict__ W2, const float* __restrict__ b2,
    const float* __restrict__ W3, const float* __restrict__ b3,
    const float* __restrict__ W4, const float* __restrict__ b4,
    const float* __restrict__ W5, const float* __restrict__ b5,
    const float* __restrict__ Wa, const float* __restrict__ ba,
    const float* __restrict__ Wo, const float* __restrict__ bo,
    float* __restrict__ out)
{
    // LDS plan (floats):
    //  [0,4352)      h1T[64][68]   (later overlaid by red[256][17])
    //  [4352,13056)  h2T[128][68]
    //  [13056,13568) small: phase1 g[64][4]+w1[64][4]; later v[256]+h4[128]+h5[64]
    __shared__ __align__(16) float smem[13568];
    __shared__ int ls_idx[SS];

    float* h1t      = smem;              // [64][68]
    float* red      = smem;              // [256][17] overlay (h1t dead after L2)
    float* h2t      = smem + 4352;       // [128][68]
    float* ls_g     = smem + 13056;      // [64][4]
    float* ls_w1    = smem + 13312;      // [64][4]
    float* ls_v     = smem + 13056;      // [256]   (g/w1 dead after L1)
    float* ls_h4    = smem + 13312;      // [128]
    float* ls_h5    = smem + 13440;      // [64]

    const int t   = threadIdx.x;
    const int blk = blockIdx.x;
    const int b   = blk >> 9;        // / 512
    const int m   = blk & 511;
    const float* xb = xyz + (size_t)b * (NN * 3);

    const float cx = xb[m*3+0], cy = xb[m*3+1], cz = xb[m*3+2];

    // new_xyz = xyz[:, :512]
    if (t < 3) out[(b*MM + m)*3 + t] = xb[m*3 + t];

    // ---- Ball query (wave 0): first 64 indices with d2 < 4.0, pad w/ first ----
    if (t < 64) {
        const int lane = t;
        int cnt = 0, base = 0, firstIdx = -1;
        while (base < NN && cnt < SS) {
            const int j = base + lane;
            const float dx = xb[j*3+0] - cx;
            const float dy = xb[j*3+1] - cy;
            const float dz = xb[j*3+2] - cz;
            // forbid fma contraction: must match the reference's mul+add rounding
            // so the idx output is bit-exact at the d2==4.0 boundary
            const float d2 = __fadd_rn(__fadd_rn(__fmul_rn(dx,dx), __fmul_rn(dy,dy)),
                                       __fmul_rn(dz,dz));
            const bool valid = d2 < 4.0f;
            const unsigned long long mask = __ballot(valid);
            if (firstIdx < 0 && mask != 0ull)
                firstIdx = base + (int)__builtin_ctzll(mask);
            const int below = __popcll(mask & ((1ull << lane) - 1ull));
            const int pos = cnt + below;
            if (valid && pos < SS) ls_idx[pos] = j;
            cnt += (int)__popcll(mask);
            if (cnt > SS) cnt = SS;
            base += 64;
        }
        if (lane >= cnt) ls_idx[lane] = firstIdx;  // cnt<64 => full scan done
    }
    __syncthreads();

    // ---- Gather g = (xyz[idx] - center)/2 ; stage W1^T+b1 ----
    if (t < 64) {
        const int p = ls_idx[t];
        out[OUT_IDX + (b*MM + m)*SS + t] = (float)p;  // idx as float (see note)
        ls_g[t*4+0] = (xb[p*3+0] - cx) * 0.5f;
        ls_g[t*4+1] = (xb[p*3+1] - cy) * 0.5f;
        ls_g[t*4+2] = (xb[p*3+2] - cz) * 0.5f;
        ls_g[t*4+3] = 0.f;
        ls_w1[t*4+0] = W1[t];        // W1 is (3,64) row-major
        ls_w1[t*4+1] = W1[64 + t];
        ls_w1[t*4+2] = W1[128 + t];
        ls_w1[t*4+3] = b1[t];
    }
    __syncthreads();

    // ---- Layer 1: h1T[c][s] = relu(g[s]·W1[:,c] + b1[c]) ----
    {
        const int s  = t & 63;
        const int cb = (t >> 6) * 16;
        const float4 g4 = *(const float4*)&ls_g[s*4];
        #pragma unroll
        for (int j = 0; j < 16; ++j) {
            const int c = cb + j;
            const float4 w = *(const float4*)&ls_w1[c*4];
            float h = fmaf(g4.x, w.x, fmaf(g4.y, w.y, fmaf(g4.z, w.z, w.w)));
            h1t[c*68 + s] = fmaxf(h, 0.f);
        }
    }
    __syncthreads();

    // ---- Layer 2: 64x128 = h1(64x64) @ W2(64x128), relu; store h2T ----
    {
        const int rt = t & 15, ct = t >> 4;
        const int s0 = rt * 4, c0 = ct * 8;
        float acc[4][8];
        #pragma unroll
        for (int i = 0; i < 4; ++i)
            #pragma unroll
            for (int j = 0; j < 8; ++j) acc[i][j] = 0.f;

        #pragma unroll 4
        for (int k = 0; k < 64; ++k) {
            const float4 h  = *(const float4*)&h1t[k*68 + s0];
            const float4 wA = *(const float4*)&W2[k*128 + c0];
            const float4 wB = *(const float4*)&W2[k*128 + c0 + 4];
            const float hv[4] = {h.x, h.y, h.z, h.w};
            const float wv[8] = {wA.x, wA.y, wA.z, wA.w, wB.x, wB.y, wB.z, wB.w};
            #pragma unroll
            for (int i = 0; i < 4; ++i)
                #pragma unroll
                for (int j = 0; j < 8; ++j)
                    acc[i][j] = fmaf(hv[i], wv[j], acc[i][j]);
        }
        #pragma unroll
        for (int j = 0; j < 8; ++j) {
            const int c = c0 + j;
            const float bias = b2[c];
            float4 o;
            o.x = fmaxf(acc[0][j] + bias, 0.f);
            o.y = fmaxf(acc[1][j] + bias, 0.f);
            o.z = fmaxf(acc[2][j] + bias, 0.f);
            o.w = fmaxf(acc[3][j] + bias, 0.f);
            *(float4*)&h2t[c*68 + s0] = o;
        }
    }
    __syncthreads();

    // ---- Layer 3: 64x256 = h2(64x128) @ W3(128x256); per-thread row max ----
    {
        const int rt = t & 15, ct = t >> 4;
        const int s0 = rt * 4, c0 = ct * 16;
        float acc[4][16];
        #pragma unroll
        for (int i = 0; i < 4; ++i)
            #pragma unroll
            for (int j = 0; j < 16; ++j) acc[i][j] = 0.f;

        #pragma unroll 2
        for (int k = 0; k < 128; ++k) {
            const float4 h = *(const float4*)&h2t[k*68 + s0];
            const float* wr = &W3[k*256 + c0];
            const float4 w0 = *(const float4*)&wr[0];
            const float4 w1_ = *(const float4*)&wr[4];
            const float4 w2_ = *(const float4*)&wr[8];
            const float4 w3_ = *(const float4*)&wr[12];
            const float hv[4] = {h.x, h.y, h.z, h.w};
            const float wv[16] = {w0.x,w0.y,w0.z,w0.w, w1_.x,w1_.y,w1_.z,w1_.w,
                                  w2_.x,w2_.y,w2_.z,w2_.w, w3_.x,w3_.y,w3_.z,w3_.w};
            #pragma unroll
            for (int i = 0; i < 4; ++i)
                #pragma unroll
                for (int j = 0; j < 16; ++j)
                    acc[i][j] = fmaf(hv[i], wv[j], acc[i][j]);
        }
        // raw max over this thread's 4 rows (bias+relu applied after pooling:
        // max_s relu(z+b) == relu(max_s z + b), relu monotone, b per-column)
        #pragma unroll
        for (int j = 0; j < 16; ++j) {
            const float mx = fmaxf(fmaxf(acc[0][j], acc[1][j]),
                                   fmaxf(acc[2][j], acc[3][j]));
            red[(c0 + j)*17 + rt] = mx;   // overlays h1t (dead)
        }
    }
    __syncthreads();

    // ---- Max-pool across row-tiles + bias + relu -> v[256] ----
    {
        const int c = t;
        float mx = red[c*17 + 0];
        #pragma unroll
        for (int r = 1; r < 16; ++r) mx = fmaxf(mx, red[c*17 + r]);
        ls_v[c] = fmaxf(mx + b3[c], 0.f);
    }
    __syncthreads();

    // ---- Layer 4: 256 -> 128 (no relu) ----
    if (t < 128) {
        float acc = b4[t];
        #pragma unroll 8
        for (int k = 0; k < 256; ++k)
            acc = fmaf(ls_v[k], W4[k*128 + t], acc);
        ls_h4[t] = acc;
    }
    __syncthreads();

    // ---- Layer 5: 128 -> 64 (no relu) ----
    if (t < 64) {
        float acc = b5[t];
        #pragma unroll 8
        for (int k = 0; k < 128; ++k)
            acc = fmaf(ls_h4[k], W5[k*64 + t], acc);
        ls_h5[t] = acc;
    }
    __syncthreads();

    // ---- Heads: attention = softplus(h5·Wa + ba); orientation = atan2(o1,o0)
    //      (o-normalization is scale-invariant under atan2 -> skip it) ----
    if (t < 64) {
        const float hv = ls_h5[t];
        float va = hv * Wa[t];
        float v0 = hv * Wo[2*t + 0];
        float v1 = hv * Wo[2*t + 1];
        #pragma unroll
        for (int off = 32; off > 0; off >>= 1) {
            va += __shfl_down(va, off);
            v0 += __shfl_down(v0, off);
            v1 += __shfl_down(v1, off);
        }
        if (t == 0) {
            const float a = va + ba[0];
            // jax.nn.softplus = logaddexp(a, 0) = max(a,0) + log1p(exp(-|a|))
            const float att = fmaxf(a, 0.f) + log1pf(expf(-fabsf(a)));
            const float o0 = v0 + bo[0];
            const float o1 = v1 + bo[1];
            out[OUT_ATT + b*MM + m] = att;
            out[OUT_ORI + b*MM + m] = atan2f(o1, o0);
        }
    }
}

extern "C" void kernel_launch(void* const* d_in, const int* in_sizes, int n_in,
                              void* d_out, int out_size, void* d_ws, size_t ws_size,
                              hipStream_t stream) {
    const float* xyz = (const float*)d_in[0];
    const float* W1  = (const float*)d_in[1];
    const float* b1  = (const float*)d_in[2];
    const float* W2  = (const float*)d_in[3];
    const float* b2  = (const float*)d_in[4];
    const float* W3  = (const float*)d_in[5];
    const float* b3  = (const float*)d_in[6];
    const float* W4  = (const float*)d_in[7];
    const float* b4  = (const float*)d_in[8];
    const float* W5  = (const float*)d_in[9];
    const float* b5  = (const float*)d_in[10];
    const float* Wa  = (const float*)d_in[11];
    const float* ba  = (const float*)d_in[12];
    const float* Wo  = (const float*)d_in[13];
    const float* bo  = (const float*)d_in[14];
    // d_in[15]=num_clusters(512), d_in[16]=num_samples(64): fixed at compile time

    feat3d_cluster_kernel<<<dim3(BB*MM), dim3(256), 0, stream>>>(
        xyz, W1, b1, W2, b2, W3, b3, W4, b4, W5, b5, Wa, ba, Wo, bo,
        (float*)d_out);
}

// Round 3
// 411.887 us; speedup vs baseline: 1.0992x; 1.0992x over previous
//
#include <hip/hip_runtime.h>
#include <math.h>

// Shapes fixed by setup_inputs(): B=8, N=8192, M=512 clusters, S=64 samples.
#define BB 8
#define NN 8192
#define MM 512
#define SS 64

// d_out layout (flat, return order): new_xyz f32[8*512*3] | idx (as f32!)[8*512*64] |
// attention f32[8*512] | orientation f32[8*512]
// NOTE: harness reads the WHOLE out buffer as float32 and compares the idx chunk
// numerically -> indices must be stored as float values, not int bit patterns.
#define OUT_IDX   (BB*MM*3)              // 12288
#define OUT_ATT   (OUT_IDX + BB*MM*SS)   // 274432
#define OUT_ORI   (OUT_ATT + BB*MM)      // 278528

__global__ __launch_bounds__(256, 3) void feat3d_cluster_kernel(
    const float* __restrict__ xyz,
    const float* __restrict__ W1, const float* __restrict__ b1,
    const float* __restrict__ W2, const float* __restrict__ b2,
    const float* __restrict__ W3, const float* __restrict__ b3,
    const float* __restrict__ W4, const float* __restrict__ b4,
    const float* __restrict__ W5, const float* __restrict__ b5,
    const float* __restrict__ Wa, const float* __restrict__ ba,
    const float* __restrict__ Wo, const float* __restrict__ bo,
    float* __restrict__ out)
{
    // LDS plan (floats), total 12800 f32 = 51200 B (+ idx/masks) -> 3 blocks/CU:
    //  [0,4096)      h1T[64][64]    (later overlaid by red[16][256])
    //  [4096,12288)  h2T[128][64]
    //  [12288,12800) phase1: g[64][4] + w1[64][4]; later v[256]+h4[128]+h5[64]
    // Bank notes: [.][64] rows give 2-way aliasing on the b128 read patterns
    // (rt vs rt+8) which is free (m136); red[r][c] reads are conflict-free.
    __shared__ __align__(16) float smem[12800];
    __shared__ int ls_idx[SS];
    __shared__ unsigned long long ls_mask[4];

    float* h1t      = smem;              // [64][64]
    float* red      = smem;              // [16][256] overlay (h1t dead after L2)
    float* h2t      = smem + 4096;       // [128][64]
    float* ls_g     = smem + 12288;      // [64][4]
    float* ls_w1    = smem + 12544;      // [64][4]
    float* ls_v     = smem + 12288;      // [256]   (g/w1 dead after L1)
    float* ls_h4    = smem + 12544;      // [128]
    float* ls_h5    = smem + 12672;      // [64]

    const int t    = threadIdx.x;
    const int wv   = t >> 6;
    const int lane = t & 63;
    const int blk  = blockIdx.x;
    const int b    = blk >> 9;       // / 512
    const int m    = blk & 511;
    const float* xb = xyz + (size_t)b * (NN * 3);

    const float cx = xb[m*3+0], cy = xb[m*3+1], cz = xb[m*3+2];

    // new_xyz = xyz[:, :512]
    if (t < 3) out[(b*MM + m)*3 + t] = xb[m*3 + t];

    // ---- Ball query, all 4 waves: first 64 indices with d2 < 4.0 (by index),
    //      pad with globally-first neighbor. 256 points per iteration. ----
    {
        int cnt = 0, base = 0, firstIdx = -1;
        while (base < NN && cnt < SS) {
            const int j = base + t;
            const float dx = xb[j*3+0] - cx;
            const float dy = xb[j*3+1] - cy;
            const float dz = xb[j*3+2] - cz;
            // forbid fma contraction: match reference mul+add rounding so the
            // idx output is exact at the d2==4.0 boundary
            const float d2 = __fadd_rn(__fadd_rn(__fmul_rn(dx,dx), __fmul_rn(dy,dy)),
                                       __fmul_rn(dz,dz));
            const bool valid = d2 < 4.0f;
            const unsigned long long mask = __ballot(valid);
            if (lane == 0) ls_mask[wv] = mask;
            __syncthreads();
            const unsigned long long m0 = ls_mask[0], m1 = ls_mask[1],
                                     m2 = ls_mask[2], m3 = ls_mask[3];
            int below = __popcll(mask & ((1ull << lane) - 1ull));
            if (wv > 0) below += (int)__popcll(m0);
            if (wv > 1) below += (int)__popcll(m1);
            if (wv > 2) below += (int)__popcll(m2);
            const int pos = cnt + below;
            if (valid && pos < SS) ls_idx[pos] = j;
            if (firstIdx < 0) {   // uniform across block (derived from masks)
                if      (m0) firstIdx = base +       (int)__builtin_ctzll(m0);
                else if (m1) firstIdx = base +  64 + (int)__builtin_ctzll(m1);
                else if (m2) firstIdx = base + 128 + (int)__builtin_ctzll(m2);
                else if (m3) firstIdx = base + 192 + (int)__builtin_ctzll(m3);
            }
            cnt += (int)(__popcll(m0) + __popcll(m1) + __popcll(m2) + __popcll(m3));
            if (cnt > SS) cnt = SS;
            base += 256;
            __syncthreads();   // ls_mask reused next iteration
        }
        if (t < SS && t >= cnt) ls_idx[t] = firstIdx;  // cnt<64 => scan finished
    }
    __syncthreads();

    // ---- Gather g = (xyz[idx] - center)/2 ; stage W1^T+b1 ----
    if (t < 64) {
        const int p = ls_idx[t];
        out[OUT_IDX + (b*MM + m)*SS + t] = (float)p;  // idx as float (see note)
        ls_g[t*4+0] = (xb[p*3+0] - cx) * 0.5f;
        ls_g[t*4+1] = (xb[p*3+1] - cy) * 0.5f;
        ls_g[t*4+2] = (xb[p*3+2] - cz) * 0.5f;
        ls_g[t*4+3] = 0.f;
        ls_w1[t*4+0] = W1[t];        // W1 is (3,64) row-major
        ls_w1[t*4+1] = W1[64 + t];
        ls_w1[t*4+2] = W1[128 + t];
        ls_w1[t*4+3] = b1[t];
    }
    __syncthreads();

    // ---- Layer 1: h1T[c][s] = relu(g[s]·W1[:,c] + b1[c]) ----
    {
        const int s  = t & 63;
        const int cb = (t >> 6) * 16;
        const float4 g4 = *(const float4*)&ls_g[s*4];
        #pragma unroll
        for (int j = 0; j < 16; ++j) {
            const int c = cb + j;
            const float4 w = *(const float4*)&ls_w1[c*4];   // wave-uniform: broadcast
            float h = fmaf(g4.x, w.x, fmaf(g4.y, w.y, fmaf(g4.z, w.z, w.w)));
            h1t[c*64 + s] = fmaxf(h, 0.f);
        }
    }
    __syncthreads();

    // ---- Layer 2: 64x128 = h1(64x64) @ W2(64x128), relu; store h2T ----
    {
        const int rt = t & 15, ct = t >> 4;
        const int s0 = rt * 4, c0 = ct * 8;
        float acc[4][8];
        #pragma unroll
        for (int i = 0; i < 4; ++i)
            #pragma unroll
            for (int j = 0; j < 8; ++j) acc[i][j] = 0.f;

        #pragma unroll 4
        for (int k = 0; k < 64; ++k) {
            const float4 h  = *(const float4*)&h1t[k*64 + s0];
            const float4 wA = *(const float4*)&W2[k*128 + c0];
            const float4 wB = *(const float4*)&W2[k*128 + c0 + 4];
            const float hv[4] = {h.x, h.y, h.z, h.w};
            const float wv_[8] = {wA.x, wA.y, wA.z, wA.w, wB.x, wB.y, wB.z, wB.w};
            #pragma unroll
            for (int i = 0; i < 4; ++i)
                #pragma unroll
                for (int j = 0; j < 8; ++j)
                    acc[i][j] = fmaf(hv[i], wv_[j], acc[i][j]);
        }
        #pragma unroll
        for (int j = 0; j < 8; ++j) {
            const int c = c0 + j;
            const float bias = b2[c];
            float4 o;
            o.x = fmaxf(acc[0][j] + bias, 0.f);
            o.y = fmaxf(acc[1][j] + bias, 0.f);
            o.z = fmaxf(acc[2][j] + bias, 0.f);
            o.w = fmaxf(acc[3][j] + bias, 0.f);
            *(float4*)&h2t[c*64 + s0] = o;
        }
    }
    __syncthreads();

    // ---- Layer 3: 64x256 = h2(64x128) @ W3(128x256); per-thread row max ----
    {
        const int rt = t & 15, ct = t >> 4;
        const int s0 = rt * 4, c0 = ct * 16;
        float acc[4][16];
        #pragma unroll
        for (int i = 0; i < 4; ++i)
            #pragma unroll
            for (int j = 0; j < 16; ++j) acc[i][j] = 0.f;

        #pragma unroll 2
        for (int k = 0; k < 128; ++k) {
            const float4 h = *(const float4*)&h2t[k*64 + s0];
            const float* wr = &W3[k*256 + c0];
            const float4 w0 = *(const float4*)&wr[0];
            const float4 w1_ = *(const float4*)&wr[4];
            const float4 w2_ = *(const float4*)&wr[8];
            const float4 w3_ = *(const float4*)&wr[12];
            const float hv[4] = {h.x, h.y, h.z, h.w};
            const float wv_[16] = {w0.x,w0.y,w0.z,w0.w, w1_.x,w1_.y,w1_.z,w1_.w,
                                   w2_.x,w2_.y,w2_.z,w2_.w, w3_.x,w3_.y,w3_.z,w3_.w};
            #pragma unroll
            for (int i = 0; i < 4; ++i)
                #pragma unroll
                for (int j = 0; j < 16; ++j)
                    acc[i][j] = fmaf(hv[i], wv_[j], acc[i][j]);
        }
        // raw max over this thread's 4 rows (bias+relu after pooling: relu
        // monotone, bias per-column => max commutes)
        #pragma unroll
        for (int j = 0; j < 16; ++j) {
            const float mx = fmaxf(fmaxf(acc[0][j], acc[1][j]),
                                   fmaxf(acc[2][j], acc[3][j]));
            red[rt*256 + c0 + j] = mx;   // red[16][256] overlays h1t (dead)
        }
    }
    __syncthreads();

    // ---- Max-pool across row-tiles + bias + relu -> v[256] ----
    {
        const int c = t;
        float mx = red[c];
        #pragma unroll
        for (int r = 1; r < 16; ++r) mx = fmaxf(mx, red[r*256 + c]);
        ls_v[c] = fmaxf(mx + b3[c], 0.f);
    }
    __syncthreads();

    // ---- Layer 4: 256 -> 128 (no relu) ----
    if (t < 128) {
        float acc = b4[t];
        #pragma unroll 8
        for (int k = 0; k < 256; ++k)
            acc = fmaf(ls_v[k], W4[k*128 + t], acc);
        ls_h4[t] = acc;
    }
    __syncthreads();

    // ---- Layer 5: 128 -> 64 (no relu) ----
    if (t < 64) {
        float acc = b5[t];
        #pragma unroll 8
        for (int k = 0; k < 128; ++k)
            acc = fmaf(ls_h4[k], W5[k*64 + t], acc);
        ls_h5[t] = acc;
    }
    __syncthreads();

    // ---- Heads: attention = softplus(h5·Wa + ba); orientation = atan2(o1,o0)
    //      (o-normalization is scale-invariant under atan2 -> skip it) ----
    if (t < 64) {
        const float hv = ls_h5[t];
        float va = hv * Wa[t];
        float v0 = hv * Wo[2*t + 0];
        float v1 = hv * Wo[2*t + 1];
        #pragma unroll
        for (int off = 32; off > 0; off >>= 1) {
            va += __shfl_down(va, off);
            v0 += __shfl_down(v0, off);
            v1 += __shfl_down(v1, off);
        }
        if (t == 0) {
            const float a = va + ba[0];
            // jax.nn.softplus = logaddexp(a, 0) = max(a,0) + log1p(exp(-|a|))
            const float att = fmaxf(a, 0.f) + log1pf(expf(-fabsf(a)));
            const float o0 = v0 + bo[0];
            const float o1 = v1 + bo[1];
            out[OUT_ATT + b*MM + m] = att;
            out[OUT_ORI + b*MM + m] = atan2f(o1, o0);
        }
    }
}

extern "C" void kernel_launch(void* const* d_in, const int* in_sizes, int n_in,
                              void* d_out, int out_size, void* d_ws, size_t ws_size,
                              hipStream_t stream) {
    const float* xyz = (const float*)d_in[0];
    const float* W1  = (const float*)d_in[1];
    const float* b1  = (const float*)d_in[2];
    const float* W2  = (const float*)d_in[3];
    const float* b2  = (const float*)d_in[4];
    const float* W3  = (const float*)d_in[5];
    const float* b3  = (const float*)d_in[6];
    const float* W4  = (const float*)d_in[7];
    const float* b4  = (const float*)d_in[8];
    const float* W5  = (const float*)d_in[9];
    const float* b5  = (const float*)d_in[10];
    const float* Wa  = (const float*)d_in[11];
    const float* ba  = (const float*)d_in[12];
    const float* Wo  = (const float*)d_in[13];
    const float* bo  = (const float*)d_in[14];
    // d_in[15]=num_clusters(512), d_in[16]=num_samples(64): fixed at compile time

    feat3d_cluster_kernel<<<dim3(BB*MM), dim3(256), 0, stream>>>(
        xyz, W1, b1, W2, b2, W3, b3, W4, b4, W5, b5, Wa, ba, Wo, bo,
        (float*)d_out);
}

// Round 4
// 155.681 us; speedup vs baseline: 2.9081x; 2.6457x over previous
//
#include <hip/hip_runtime.h>
#include <math.h>

// Shapes fixed by setup_inputs(): B=8, N=8192, M=512 clusters, S=64 samples.
#define BB 8
#define NN 8192
#define MM 512
#define SS 64

// d_out layout (flat, return order, all read back as f32):
// new_xyz[8*512*3] | idx(as float)[8*512*64] | attention[8*512] | orientation[8*512]
#define OUT_IDX   (BB*MM*3)              // 12288
#define OUT_ATT   (OUT_IDX + BB*MM*SS)   // 274432
#define OUT_ORI   (OUT_ATT + BB*MM)      // 278528

typedef short v8s __attribute__((ext_vector_type(8)));   // 8 bf16 = 4 VGPRs (MFMA A/B frag)
typedef float v4f __attribute__((ext_vector_type(4)));   // MFMA C/D frag

static __device__ __forceinline__ unsigned short f2bf(float x) {
    unsigned int u = __float_as_uint(x);
    u += 0x7FFFu + ((u >> 16) & 1u);     // round-to-nearest-even
    return (unsigned short)(u >> 16);
}

// ---- Kernel 0: pack W2 (64x128) and W3 (128x256) fp32 -> bf16 MFMA B-fragment
// layout in d_ws.  For mfma_f32_16x16x32_bf16, B-frag lane l holds
// B[kt*32 + (l>>4)*8 + j][nt*16 + (l&15)], j=0..7 -> stored as 8 contiguous bf16
// at frag (tile*64 + l).  W2: tiles kt(2) x nt(8); W3: kt(4) x nt(16).
__global__ void pack_weights(const float* __restrict__ W2,
                             const float* __restrict__ W3,
                             unsigned short* __restrict__ ws)
{
    const int gid = blockIdx.x * 256 + threadIdx.x;    // 0..5119
    const float* W; unsigned short* dst; int N, kt, nt, lane;
    if (gid < 1024) {                   // W2: 16 tiles * 64 lanes
        W = W2; N = 128;
        const int tile = gid >> 6; lane = gid & 63;
        kt = tile >> 3; nt = tile & 7;
        dst = ws + (size_t)(tile * 64 + lane) * 8;
    } else {                            // W3: 64 tiles * 64 lanes
        const int g = gid - 1024;
        W = W3; N = 256;
        const int tile = g >> 6; lane = g & 63;
        kt = tile >> 4; nt = tile & 15;
        dst = ws + 8192 + (size_t)(tile * 64 + lane) * 8;
    }
    const int k0 = kt * 32 + (lane >> 4) * 8;
    const int n  = nt * 16 + (lane & 15);
    union { unsigned short u[8]; v8s v; } f;
    #pragma unroll
    for (int j = 0; j < 8; ++j) f.u[j] = f2bf(W[(k0 + j) * N + n]);
    *(v8s*)dst = f.v;
}

// ---- Main kernel: one block per cluster ----
__global__ __launch_bounds__(256, 3) void feat3d_main(
    const float* __restrict__ xyz,
    const float* __restrict__ W1, const float* __restrict__ b1,
    const float* __restrict__ b2, const float* __restrict__ b3,
    const float* __restrict__ W4, const float* __restrict__ b4,
    const float* __restrict__ W5, const float* __restrict__ b5,
    const float* __restrict__ Wa, const float* __restrict__ ba,
    const float* __restrict__ Wo, const float* __restrict__ bo,
    const unsigned short* __restrict__ Wp,   // packed bf16: W2 frags | W3 frags
    float* __restrict__ out)
{
    // LDS ~28 KB total -> 3 blocks/CU (VGPR-capped anyway).
    __shared__ __align__(16) unsigned short a2p[8 * 64 * 8];    // h1 A-frags, 8 KB
    __shared__ __align__(16) unsigned short a3p[16 * 64 * 8];   // h2 A-frags, 16 KB
    __shared__ __align__(16) float smallf[512];                 // 2 KB, phased
    __shared__ int ls_idx[SS];
    __shared__ unsigned long long ls_mask[4];

    float* ls_g  = smallf;         // [64][4]  (gather/L1 phase)
    float* ls_w1 = smallf + 256;   // [64][4]  (gather/L1 phase)
    float* ls_v  = smallf;         // [256]    (pool onward; g dead)
    float* ls_h4 = smallf + 256;   // [128]
    float* ls_h5 = smallf + 384;   // [64]

    const int t   = threadIdx.x;
    const int wv  = t >> 6;        // wave 0..3
    const int l   = t & 63;        // lane
    const int q   = l >> 4;        // quad 0..3
    const int r16 = l & 15;
    const int blk = blockIdx.x;
    const int b   = blk >> 9;
    const int m   = blk & 511;
    const float* xb = xyz + (size_t)b * (NN * 3);

    const float cx = xb[m*3+0], cy = xb[m*3+1], cz = xb[m*3+2];

    if (t < 3) out[(b*MM + m)*3 + t] = xb[m*3 + t];   // new_xyz

    // ---- Ball query (all 4 waves, 256 pts/iter): first 64 idx with d2<4,
    //      pad with globally-first neighbor ----
    {
        int cnt = 0, base = 0, firstIdx = -1;
        while (base < NN && cnt < SS) {
            const int j = base + t;
            const float dx = xb[j*3+0] - cx;
            const float dy = xb[j*3+1] - cy;
            const float dz = xb[j*3+2] - cz;
            // no fma contraction: idx must be exact at the d2==4.0 boundary
            const float d2 = __fadd_rn(__fadd_rn(__fmul_rn(dx,dx), __fmul_rn(dy,dy)),
                                       __fmul_rn(dz,dz));
            const bool valid = d2 < 4.0f;
            const unsigned long long mask = __ballot(valid);
            if (l == 0) ls_mask[wv] = mask;
            __syncthreads();
            const unsigned long long m0 = ls_mask[0], m1 = ls_mask[1],
                                     m2 = ls_mask[2], m3 = ls_mask[3];
            int below = __popcll(mask & ((1ull << l) - 1ull));
            if (wv > 0) below += (int)__popcll(m0);
            if (wv > 1) below += (int)__popcll(m1);
            if (wv > 2) below += (int)__popcll(m2);
            const int pos = cnt + below;
            if (valid && pos < SS) ls_idx[pos] = j;
            if (firstIdx < 0) {
                if      (m0) firstIdx = base +       (int)__builtin_ctzll(m0);
                else if (m1) firstIdx = base +  64 + (int)__builtin_ctzll(m1);
                else if (m2) firstIdx = base + 128 + (int)__builtin_ctzll(m2);
                else if (m3) firstIdx = base + 192 + (int)__builtin_ctzll(m3);
            }
            cnt += (int)(__popcll(m0) + __popcll(m1) + __popcll(m2) + __popcll(m3));
            if (cnt > SS) cnt = SS;
            base += 256;
            __syncthreads();
        }
        if (t < SS && t >= cnt) ls_idx[t] = firstIdx;
    }
    __syncthreads();

    // ---- Gather g = (xyz[idx]-center)/2 ; stage W1^T + b1 ----
    if (t < 64) {
        const int p = ls_idx[t];
        out[OUT_IDX + (b*MM + m)*SS + t] = (float)p;  // idx stored as float
        ls_g[t*4+0] = (xb[p*3+0] - cx) * 0.5f;
        ls_g[t*4+1] = (xb[p*3+1] - cy) * 0.5f;
        ls_g[t*4+2] = (xb[p*3+2] - cz) * 0.5f;
        ls_g[t*4+3] = 0.f;
        ls_w1[t*4+0] = W1[t];
        ls_w1[t*4+1] = W1[64 + t];
        ls_w1[t*4+2] = W1[128 + t];
        ls_w1[t*4+3] = b1[t];
    }
    __syncthreads();

    // ---- L1 (fp32) + pack h1 into A-fragment layout:
    // lane l of wave wv produces s = wv*16+r16, c = kt*32+q*8+j  (2 frags) ----
    {
        const int s = wv*16 + r16;
        const float4 g4 = *(const float4*)&ls_g[s*4];
        #pragma unroll
        for (int kt = 0; kt < 2; ++kt) {
            union { unsigned short u[8]; v8s v; } fr;
            #pragma unroll
            for (int j = 0; j < 8; ++j) {
                const int c = kt*32 + q*8 + j;
                const float4 w = *(const float4*)&ls_w1[c*4];
                const float h = fmaf(g4.x, w.x, fmaf(g4.y, w.y, fmaf(g4.z, w.z, w.w)));
                fr.u[j] = f2bf(fmaxf(h, 0.f));
            }
            *(v8s*)&a2p[((kt*4 + wv)*64 + l)*8] = fr.v;
        }
    }
    __syncthreads();

    // ---- L2 MFMA: h2(64x128) = relu(h1 @ W2 + b2). Wave wv owns nt {2wv,2wv+1}.
    {
        const v8s* W2f = (const v8s*)Wp;            // frag index (kt*8+nt)*64+l
        v8s bfr[2][2];
        #pragma unroll
        for (int kt = 0; kt < 2; ++kt)
            #pragma unroll
            for (int ni = 0; ni < 2; ++ni)
                bfr[kt][ni] = W2f[(kt*8 + 2*wv + ni)*64 + l];

        const v4f z = {0.f, 0.f, 0.f, 0.f};
        v4f acc[4][2];
        #pragma unroll
        for (int mt = 0; mt < 4; ++mt) { acc[mt][0] = z; acc[mt][1] = z; }

        #pragma unroll
        for (int kt = 0; kt < 2; ++kt)
            #pragma unroll
            for (int mt = 0; mt < 4; ++mt) {
                const v8s a = *(const v8s*)&a2p[((kt*4 + mt)*64 + l)*8];
                #pragma unroll
                for (int ni = 0; ni < 2; ++ni)
                    acc[mt][ni] = __builtin_amdgcn_mfma_f32_16x16x32_bf16(
                        a, bfr[kt][ni], acc[mt][ni], 0, 0, 0);
            }

        // Epilogue: +b2, relu, cvt bf16, scatter into L3 A-frag layout.
        // C/D elem (mt,ni,rg): s = mt*16+q*4+rg, c2 = (2wv+ni)*16+r16.
        // A3 target: tile ( (c2>>5)*4 + mt ), lane (s&15)|(((c2>>3)&3)<<4), j = c2&7.
        #pragma unroll
        for (int ni = 0; ni < 2; ++ni) {
            const int c2  = (2*wv + ni)*16 + r16;
            const float bias = b2[c2];
            const int kt3 = c2 >> 5;
            const int lhi = ((c2 >> 3) & 3) << 4;
            const int j3  = c2 & 7;
            #pragma unroll
            for (int mt = 0; mt < 4; ++mt)
                #pragma unroll
                for (int rg = 0; rg < 4; ++rg) {
                    const float h = fmaxf(acc[mt][ni][rg] + bias, 0.f);
                    const int s15 = q*4 + rg;
                    a3p[((kt3*4 + mt)*64 + (lhi | s15))*8 + j3] = f2bf(h);
                }
        }
    }
    __syncthreads();

    // ---- L3 MFMA: h3raw(64x256) = h2 @ W3. Wave wv owns nt {4wv..4wv+3}.
    //      Then max-pool over s entirely in registers + shuffles. ----
    {
        const v8s* W3f = (const v8s*)(Wp + 8192);   // frag index (kt*16+nt)*64+l
        const v4f z = {0.f, 0.f, 0.f, 0.f};
        v4f acc[4][4];
        #pragma unroll
        for (int mt = 0; mt < 4; ++mt)
            #pragma unroll
            for (int ni = 0; ni < 4; ++ni) acc[mt][ni] = z;

        #pragma unroll
        for (int kt = 0; kt < 4; ++kt) {
            v8s a[4], bb[4];
            #pragma unroll
            for (int mt = 0; mt < 4; ++mt)
                a[mt] = *(const v8s*)&a3p[((kt*4 + mt)*64 + l)*8];
            #pragma unroll
            for (int ni = 0; ni < 4; ++ni)
                bb[ni] = W3f[(kt*16 + 4*wv + ni)*64 + l];
            #pragma unroll
            for (int mt = 0; mt < 4; ++mt)
                #pragma unroll
                for (int ni = 0; ni < 4; ++ni)
                    acc[mt][ni] = __builtin_amdgcn_mfma_f32_16x16x32_bf16(
                        a[mt], bb[ni], acc[mt][ni], 0, 0, 0);
        }

        // Pool: lane holds rows s = mt*16+q*4+rg for col c = (4wv+ni)*16+r16.
        // max over 16 regs, then over quads via shfl_xor; bias+relu after pool
        // (relu monotone, bias per-column => commutes).
        #pragma unroll
        for (int ni = 0; ni < 4; ++ni) {
            float mx = acc[0][ni][0];
            #pragma unroll
            for (int mt = 0; mt < 4; ++mt)
                #pragma unroll
                for (int rg = 0; rg < 4; ++rg)
                    mx = fmaxf(mx, acc[mt][ni][rg]);
            mx = fmaxf(mx, __shfl_xor(mx, 16));
            mx = fmaxf(mx, __shfl_xor(mx, 32));
            if (q == 0) {
                const int c = (4*wv + ni)*16 + r16;
                ls_v[c] = fmaxf(mx + b3[c], 0.f);
            }
        }
    }
    __syncthreads();

    // ---- L4: 256 -> 128 (fp32, no relu) ----
    if (t < 128) {
        float acc = b4[t];
        #pragma unroll 8
        for (int k = 0; k < 256; ++k)
            acc = fmaf(ls_v[k], W4[k*128 + t], acc);
        ls_h4[t] = acc;
    }
    __syncthreads();

    // ---- L5: 128 -> 64 (fp32, no relu) ----
    if (t < 64) {
        float acc = b5[t];
        #pragma unroll 8
        for (int k = 0; k < 128; ++k)
            acc = fmaf(ls_h4[k], W5[k*64 + t], acc);
        ls_h5[t] = acc;
    }
    __syncthreads();

    // ---- Heads: attention = softplus(h5·Wa+ba); orientation = atan2(o1,o0)
    //      (normalization of o is scale-invariant under atan2 -> skipped) ----
    if (t < 64) {
        const float hv = ls_h5[t];
        float va = hv * Wa[t];
        float v0 = hv * Wo[2*t + 0];
        float v1 = hv * Wo[2*t + 1];
        #pragma unroll
        for (int off = 32; off > 0; off >>= 1) {
            va += __shfl_down(va, off);
            v0 += __shfl_down(v0, off);
            v1 += __shfl_down(v1, off);
        }
        if (t == 0) {
            const float a = va + ba[0];
            const float att = fmaxf(a, 0.f) + log1pf(expf(-fabsf(a)));
            out[OUT_ATT + b*MM + m] = att;
            out[OUT_ORI + b*MM + m] = atan2f(v1 + bo[1], v0 + bo[0]);
        }
    }
}

extern "C" void kernel_launch(void* const* d_in, const int* in_sizes, int n_in,
                              void* d_out, int out_size, void* d_ws, size_t ws_size,
                              hipStream_t stream) {
    const float* xyz = (const float*)d_in[0];
    const float* W1  = (const float*)d_in[1];
    const float* b1  = (const float*)d_in[2];
    const float* W2  = (const float*)d_in[3];
    const float* b2  = (const float*)d_in[4];
    const float* W3  = (const float*)d_in[5];
    const float* b3  = (const float*)d_in[6];
    const float* W4  = (const float*)d_in[7];
    const float* b4  = (const float*)d_in[8];
    const float* W5  = (const float*)d_in[9];
    const float* b5  = (const float*)d_in[10];
    const float* Wa  = (const float*)d_in[11];
    const float* ba  = (const float*)d_in[12];
    const float* Wo  = (const float*)d_in[13];
    const float* bo  = (const float*)d_in[14];

    unsigned short* Wp = (unsigned short*)d_ws;   // 16 KB (W2) + 64 KB (W3)

    pack_weights<<<dim3(20), dim3(256), 0, stream>>>(W2, W3, Wp);
    feat3d_main<<<dim3(BB*MM), dim3(256), 0, stream>>>(
        xyz, W1, b1, b2, b3, W4, b4, W5, b5, Wa, ba, Wo, bo, Wp, (float*)d_out);
}